// Round 1
// 799.513 us; speedup vs baseline: 1.0702x; 1.0702x over previous
//
#include <hip/hip_runtime.h>
#include <stdint.h>

#define D 128
#define NROWS 300000
#define MIDX 262144
#define SBH 132                 // padded row stride (elements) for LDS transpose buffers
#define WAVE_BUF (16 * SBH)     // floats per wave buffer

typedef __attribute__((ext_vector_type(8))) short short8_t;
typedef __attribute__((ext_vector_type(4))) short short4_t;
typedef __attribute__((ext_vector_type(4))) float float4v;

__device__ __forceinline__ short f2bf(float x) {
  uint32_t u = __float_as_uint(x);
  u = (u + 0x7FFFu + ((u >> 16) & 1u)) >> 16;   // round-to-nearest-even
  return (short)u;
}

// ---------------- pass 1: last-write-wins winners ----------------
__global__ void winners_kernel(const int* __restrict__ idx_p,
                               const int* __restrict__ idx_k,
                               int* __restrict__ wp, int* __restrict__ wk) {
  int m = blockIdx.x * 256 + threadIdx.x;
  if (m < MIDX) {
    atomicMax(&wp[idx_p[m]], m);
    atomicMax(&wk[idx_k[m]], m);
  }
}

// ---------------- pass 1b: copy NON-winner rows straight through ----------------
// Winner rows (wp[i] >= 0) are written by fused_kernel's scatter; everything else
// is an identity passthrough of h_p/h_k. Replaces two 153.6MB hipMemcpyAsync D2D
// nodes (which also redundantly wrote the ~175K winner rows).
// One thread = one float4; 32 threads per row; a wave covers 2 rows.
__global__ __launch_bounds__(256)
void copyrest_kernel(const float* __restrict__ h_p, const float* __restrict__ h_k,
                     const int* __restrict__ wp, const int* __restrict__ wk,
                     float* __restrict__ out_p, float* __restrict__ out_k) {
  int g = blockIdx.x * 256 + threadIdx.x;
  int row = g >> 5;
  if (row >= NROWS) return;
  int c = (g & 31) << 2;
  size_t off = (size_t)row * D + c;
  if (wp[row] < 0) *(float4v*)(out_p + off) = *(const float4v*)(h_p + off);
  if (wk[row] < 0) *(float4v*)(out_k + off) = *(const float4v*)(h_k + off);
}

// ---------------- pass 2: pack weights into MFMA B-fragment layout ----------------
// B-frag for (tile t, kstep s): lane holds B[k=32s+8q+j][n=16t+l15], j=0..7,
// stored contiguously at ((t*4+s)*64+lane)*8  -> 16B coalesced loads in the GEMM.
// trans=1: B[k][n] = W[n][k]  (x @ W.T GEMMs, W is 128x128 row-major)
// trans=0: B[k][n] = W[k][n]  (x @ W GEMMs, W is 128x64 row-major)
__global__ void pack_kernel(const float* __restrict__ Wq, const float* __restrict__ Wk,
                            const float* __restrict__ Wv, const float* __restrict__ W1,
                            const float* __restrict__ Wl, const float* __restrict__ Wo,
                            const float* __restrict__ Wp, short* __restrict__ dst) {
  int slot = blockIdx.x;
  int lane = threadIdx.x;
  const float* W; int base; int trans; int rel;
  if      (slot < 32)  { W = Wq; base = 0;     trans = 1; rel = slot; }
  else if (slot < 64)  { W = Wk; base = 16384; trans = 1; rel = slot - 32; }
  else if (slot < 96)  { W = Wv; base = 32768; trans = 1; rel = slot - 64; }
  else if (slot < 128) { W = W1; base = 49152; trans = 1; rel = slot - 96; }
  else if (slot < 160) { W = Wl; base = 65536; trans = 1; rel = slot - 128; }
  else if (slot < 176) { W = Wo; base = 81920; trans = 0; rel = slot - 160; }
  else                 { W = Wp; base = 90112; trans = 0; rel = slot - 176; }
  int t = rel >> 2, s = rel & 3;
  int n = 16 * t + (lane & 15);
  int kb = 32 * s + 8 * (lane >> 4);
  short* o = dst + base + (size_t)(rel * 64 + lane) * 8;
  #pragma unroll
  for (int j = 0; j < 8; j++) {
    float v = trans ? W[n * 128 + kb + j] : W[(kb + j) * 64 + n];
    o[j] = f2bf(v);
  }
}

// ---------------- fused compute ----------------
__device__ __forceinline__ float4v gemm_tile(const short8_t a[4], const short* __restrict__ B,
                                             int t, int lane) {
  float4v acc = {0.f, 0.f, 0.f, 0.f};
  #pragma unroll
  for (int s = 0; s < 4; s++) {
    short8_t b = *(const short8_t*)(B + (size_t)((t * 4 + s) * 64 + lane) * 8);
    acc = __builtin_amdgcn_mfma_f32_16x16x32_bf16(a[s], b, acc, 0, 0, 0);
  }
  return acc;
}

// gather one 128-f32 row into A-operand bf16 fragments (m=l15, k=8q+32s+j)
__device__ __forceinline__ void load_row_frags(const float* __restrict__ row, int q, short8_t out[4]) {
  #pragma unroll
  for (int s = 0; s < 4; s++) {
    float4v v0 = *(const float4v*)(row + 32 * s + 8 * q);
    float4v v1 = *(const float4v*)(row + 32 * s + 8 * q + 4);
    short8_t r;
    r[0] = f2bf(v0[0]); r[1] = f2bf(v0[1]); r[2] = f2bf(v0[2]); r[3] = f2bf(v0[3]);
    r[4] = f2bf(v1[0]); r[5] = f2bf(v1[1]); r[6] = f2bf(v1[2]); r[7] = f2bf(v1[3]);
    out[s] = r;
  }
}

__device__ __forceinline__ void read_a_frags(const short* __restrict__ sb, int l15, int q, short8_t out[4]) {
  #pragma unroll
  for (int s = 0; s < 4; s++) {
    const short* p = sb + l15 * SBH + 32 * s + 8 * q;
    short4_t lo = *(const short4_t*)p;
    short4_t hi = *(const short4_t*)(p + 4);
    short8_t v;
    v[0] = lo[0]; v[1] = lo[1]; v[2] = lo[2]; v[3] = lo[3];
    v[4] = hi[0]; v[5] = hi[1]; v[6] = hi[2]; v[7] = hi[3];
    out[s] = v;
  }
}

__device__ __forceinline__ float red16(float v) {
  v += __shfl_xor(v, 1);
  v += __shfl_xor(v, 2);
  v += __shfl_xor(v, 4);
  v += __shfl_xor(v, 8);
  return v;
}

__global__ __launch_bounds__(256, 2)
void fused_kernel(const float* __restrict__ h_p, const float* __restrict__ h_k,
                  const float* __restrict__ h_o, int ho_rows,
                  const int* __restrict__ idx_p, const int* __restrict__ idx_k,
                  const short* __restrict__ wbuf,
                  const float* __restrict__ bq, const float* __restrict__ bk,
                  const float* __restrict__ bv, const float* __restrict__ b1,
                  const float* __restrict__ linb, const float* __restrict__ bias,
                  const float* __restrict__ lng, const float* __restrict__ lnb,
                  const int* __restrict__ wp, const int* __restrict__ wk,
                  float* __restrict__ out_p, float* __restrict__ out_k)
{
  const short* Bq_ = wbuf;
  const short* Bk_ = wbuf + 16384;
  const short* Bv_ = wbuf + 32768;
  const short* B1_ = wbuf + 49152;
  const short* Bl_ = wbuf + 65536;
  const short* Bo_ = wbuf + 81920;
  const short* Bp_ = wbuf + 90112;

  __shared__ float smem[4 * WAVE_BUF];
  const int tid  = threadIdx.x;
  const int wave = tid >> 6;
  const int lane = tid & 63;
  const int l15  = lane & 15;
  const int q    = lane >> 4;

  float* fbuf = smem + wave * WAVE_BUF;   // per-wave private buffer, no __syncthreads needed
  short* sbuf = (short*)fbuf;

  const int m0   = blockIdx.x * 64 + wave * 16;   // this wave's 16 rows
  const int mrow = m0 + l15;
  const int ip = idx_p[mrow];
  const int ik = idx_k[mrow];
  // JAX promise_in_bounds gather: out-of-bounds h_o indices CLAMP (idx in [0,N=300000)
  // but h_o has only ho_rows=262144 rows). Without this clamp we page-fault.
  const int ipo = (ip < ho_rows) ? ip : (ho_rows - 1);

  short8_t aho[4], ahp[4], ahk[4];
  load_row_frags(h_o + (size_t)ipo * D, q, aho);
  load_row_frags(h_p + (size_t)ip * D, q, ahp);
  load_row_frags(h_k + (size_t)ik * D, q, ahk);

  // ---- Q = ho_sel @ Wq.T + bq ----
  float4v Q[8];
  #pragma unroll
  for (int t = 0; t < 8; t++) {
    Q[t] = gemm_tile(aho, Bq_, t, lane) + bq[16 * t + l15];
  }

  // ---- logits s0,s1 (row-wise dot of Q with K0,K1) ----
  float4v p0 = {0,0,0,0}, p1 = {0,0,0,0};
  #pragma unroll
  for (int t = 0; t < 8; t++) {
    float bkv = bk[16 * t + l15];
    float4v k0 = gemm_tile(ahp, Bk_, t, lane) + bkv;
    float4v k1 = gemm_tile(ahk, Bk_, t, lane) + bkv;
    p0 += Q[t] * k0;
    p1 += Q[t] * k1;
  }
  float a0[4], a1[4];
  #pragma unroll
  for (int r = 0; r < 4; r++) {
    float s0 = red16(p0[r]) * 0.08838834764831845f;   // D^-0.5
    float s1 = red16(p1[r]) * 0.08838834764831845f;
    float mx = fmaxf(s0, s1);
    float e0 = __expf(s0 - mx), e1 = __expf(s1 - mx);
    float inv = 1.0f / (e0 + e1);
    a0[r] = e0 * inv;
    a1[r] = e1 * inv;
  }

  // ---- ctx = a0*V0 + a1*V1 ----
  float4v ctx[8];
  #pragma unroll
  for (int t = 0; t < 8; t++) {
    float bvv = bv[16 * t + l15];
    float4v v0 = gemm_tile(ahp, Bv_, t, lane) + bvv;
    float4v v1 = gemm_tile(ahk, Bv_, t, lane) + bvv;
    float4v c;
    #pragma unroll
    for (int r = 0; r < 4; r++) c[r] = a0[r] * v0[r] + a1[r] * v1[r];
    ctx[t] = c;
  }

  // ---- LDS round trip 1: ctx C-layout -> A-layout ----
  #pragma unroll
  for (int t = 0; t < 8; t++)
    #pragma unroll
    for (int r = 0; r < 4; r++)
      sbuf[(4 * q + r) * SBH + 16 * t + l15] = f2bf(ctx[t][r]);
  short8_t afu[4];
  read_a_frags(sbuf, l15, q, afu);

  // ---- fusion = ctx @ W1.T + b1, then LayerNorm ----
  float4v F[8];
  float4v sum = {0,0,0,0}, ssq = {0,0,0,0};
  #pragma unroll
  for (int t = 0; t < 8; t++) {
    float4v f = gemm_tile(afu, B1_, t, lane) + b1[16 * t + l15];
    F[t] = f;
    sum += f;
    ssq += f * f;
  }
  #pragma unroll
  for (int r = 0; r < 4; r++) {
    float s  = red16(sum[r]);
    float s2 = red16(ssq[r]);
    float mu  = s * (1.0f / 128.0f);
    float var = s2 * (1.0f / 128.0f) - mu * mu;
    float rs  = rsqrtf(var + 1e-5f);
    #pragma unroll
    for (int t = 0; t < 8; t++) F[t][r] = (F[t][r] - mu) * rs;
  }
  // apply gamma/beta, round trip 2
  #pragma unroll
  for (int t = 0; t < 8; t++) {
    int col = 16 * t + l15;
    float g = lng[col], b = lnb[col];
    #pragma unroll
    for (int r = 0; r < 4; r++)
      sbuf[(4 * q + r) * SBH + col] = f2bf(F[t][r] * g + b);
  }
  short8_t afn[4];
  read_a_frags(sbuf, l15, q, afn);

  // ---- u = tanh([ho_sel@weight_o , fusion@weight_p]) ----
  float4v U[8];
  #pragma unroll
  for (int t = 0; t < 4; t++) U[t]     = gemm_tile(aho, Bo_, t, lane);
  #pragma unroll
  for (int t = 0; t < 4; t++) U[4 + t] = gemm_tile(afn, Bp_, t, lane);
  #pragma unroll
  for (int t = 0; t < 8; t++) {
    #pragma unroll
    for (int r = 0; r < 4; r++) {
      float x  = U[t][r];
      float e  = __expf(-2.0f * fabsf(x));
      float th = (1.0f - e) / (1.0f + e);
      sbuf[(4 * q + r) * SBH + 16 * t + l15] = f2bf(copysignf(th, x));  // round trip 3
    }
  }
  short8_t au[4];
  read_a_frags(sbuf, l15, q, au);

  // ---- out = leaky_relu(u @ lin_W.T + lin_b) + bias  -> LDS fp32 ----
  #pragma unroll
  for (int t = 0; t < 8; t++) {
    int col = 16 * t + l15;
    float4v z = gemm_tile(au, Bl_, t, lane) + linb[col];
    float bb = bias[col];
    #pragma unroll
    for (int r = 0; r < 4; r++) {
      float x = z[r];
      x = (x > 0.0f) ? x : 0.01f * x;
      fbuf[(4 * q + r) * SBH + col] = x + bb;
    }
  }

  // ---- winner-checked scatter (4 lanes per row, 128B each) ----
  int r_out = lane >> 2;
  int cb    = (lane & 3) * 32;
  int mg    = m0 + r_out;
  int ip2 = idx_p[mg];
  int ik2 = idx_k[mg];
  bool dop = (wp[ip2] == mg);
  bool dok = (wk[ik2] == mg);
  const float* src = fbuf + r_out * SBH + cb;
  float* dp = out_p + (size_t)ip2 * D + cb;
  float* dk = out_k + (size_t)ik2 * D + cb;
  #pragma unroll
  for (int c = 0; c < 32; c += 4) {
    float4v v = *(const float4v*)(src + c);
    if (dop) *(float4v*)(dp + c) = v;
    if (dok) *(float4v*)(dk + c) = v;
  }
}

extern "C" void kernel_launch(void* const* d_in, const int* in_sizes, int n_in,
                              void* d_out, int out_size, void* d_ws, size_t ws_size,
                              hipStream_t stream) {
  const float* h_p      = (const float*)d_in[0];
  const float* h_k      = (const float*)d_in[1];
  const float* h_o      = (const float*)d_in[2];
  const float* weight_o = (const float*)d_in[3];
  const float* weight_p = (const float*)d_in[4];
  const float* lin_W    = (const float*)d_in[5];
  const float* lin_b    = (const float*)d_in[6];
  const float* bias     = (const float*)d_in[7];
  const float* Wq       = (const float*)d_in[8];
  const float* bq       = (const float*)d_in[9];
  const float* Wk       = (const float*)d_in[10];
  const float* bk       = (const float*)d_in[11];
  const float* Wv       = (const float*)d_in[12];
  const float* bv       = (const float*)d_in[13];
  const float* W1       = (const float*)d_in[14];
  const float* b1       = (const float*)d_in[15];
  const float* ln_g     = (const float*)d_in[16];
  const float* ln_b     = (const float*)d_in[17];
  const int*   idx_p    = (const int*)d_in[18];
  const int*   idx_k    = (const int*)d_in[19];

  const int ho_rows = in_sizes[2] / D;   // 262144 — NOT NROWS; indices must clamp

  float* out_p = (float*)d_out;
  float* out_k = out_p + (size_t)NROWS * D;

  int* wp = (int*)d_ws;
  int* wk = wp + NROWS;
  short* wbuf = (short*)((char*)d_ws + (size_t)2 * NROWS * 4);  // 2.4MB in, 16B aligned

  hipMemsetAsync(wp, 0xFF, (size_t)2 * NROWS * sizeof(int), stream);   // winners = -1

  winners_kernel<<<dim3(MIDX / 256), dim3(256), 0, stream>>>(idx_p, idx_k, wp, wk);
  // non-winner rows pass through h_p/h_k; winner rows are written by fused_kernel's scatter
  copyrest_kernel<<<dim3((NROWS * 32 + 255) / 256), dim3(256), 0, stream>>>(
      h_p, h_k, wp, wk, out_p, out_k);
  pack_kernel<<<dim3(192), dim3(64), 0, stream>>>(Wq, Wk, Wv, W1, lin_W, weight_o, weight_p, wbuf);
  fused_kernel<<<dim3(MIDX / 64), dim3(256), 0, stream>>>(
      h_p, h_k, h_o, ho_rows, idx_p, idx_k, wbuf, bq, bk, bv, b1, lin_b, bias, ln_g, ln_b,
      wp, wk, out_p, out_k);
}